// Round 1
// baseline (717.874 us; speedup 1.0000x reference)
//
#include <hip/hip_runtime.h>
#include <math.h>

// Problem constants
#define Bn 8
#define Ln 512
#define Hn 512
#define NHn 8
#define DHn 64

// ---------------------------------------------------------------------------
// Kernel 1: fused projection GEMMs (NT): Y[m,n] = sum_k X[m,k]*W[n,k] + b[n]
// z=0: Q = src@Wq^T+bq ; z=1: K ; z=2: V ; z=3: Rp = pe@Wr^T+br
// 64x64 tile, BK=16, 256 threads, 4x4 per thread.
// ---------------------------------------------------------------------------
__global__ __launch_bounds__(256) void proj_kernel(
    const float* __restrict__ src, const float* __restrict__ pe,
    const float* __restrict__ Wq, const float* __restrict__ bq,
    const float* __restrict__ Wk, const float* __restrict__ bk,
    const float* __restrict__ Wv, const float* __restrict__ bv,
    const float* __restrict__ Wr, const float* __restrict__ br,
    float* __restrict__ Qb, float* __restrict__ Kb, float* __restrict__ Vb,
    float* __restrict__ Rp)
{
    const float* X; const float* W; const float* bias; float* Y; int M;
    switch (blockIdx.z) {
      case 0:  X = src; W = Wq; bias = bq; Y = Qb; M = Bn * Ln; break;
      case 1:  X = src; W = Wk; bias = bk; Y = Kb; M = Bn * Ln; break;
      case 2:  X = src; W = Wv; bias = bv; Y = Vb; M = Bn * Ln; break;
      default: X = pe;  W = Wr; bias = br; Y = Rp; M = 2 * Ln;  break;
    }
    const int m0 = blockIdx.y * 64;
    if (m0 >= M) return;
    const int n0 = blockIdx.x * 64;

    __shared__ float Xs[16][65];   // [k][m]
    __shared__ float Ws[16][65];   // [k][n]

    const int tid = threadIdx.x;
    const int tx = tid & 15, ty = tid >> 4;
    const int lrow = tid >> 2;          // 0..63
    const int lc4  = (tid & 3) * 4;     // 0,4,8,12

    float acc[4][4] = {};

    for (int k0 = 0; k0 < 512; k0 += 16) {
        float4 xv = *reinterpret_cast<const float4*>(&X[(size_t)(m0 + lrow) * 512 + k0 + lc4]);
        float4 wv = *reinterpret_cast<const float4*>(&W[(size_t)(n0 + lrow) * 512 + k0 + lc4]);
        Xs[lc4 + 0][lrow] = xv.x; Xs[lc4 + 1][lrow] = xv.y;
        Xs[lc4 + 2][lrow] = xv.z; Xs[lc4 + 3][lrow] = xv.w;
        Ws[lc4 + 0][lrow] = wv.x; Ws[lc4 + 1][lrow] = wv.y;
        Ws[lc4 + 2][lrow] = wv.z; Ws[lc4 + 3][lrow] = wv.w;
        __syncthreads();
        #pragma unroll
        for (int k = 0; k < 16; ++k) {
            float a0 = Xs[k][ty * 4 + 0], a1 = Xs[k][ty * 4 + 1];
            float a2 = Xs[k][ty * 4 + 2], a3 = Xs[k][ty * 4 + 3];
            float b0 = Ws[k][tx * 4 + 0], b1 = Ws[k][tx * 4 + 1];
            float b2 = Ws[k][tx * 4 + 2], b3 = Ws[k][tx * 4 + 3];
            acc[0][0] += a0 * b0; acc[0][1] += a0 * b1; acc[0][2] += a0 * b2; acc[0][3] += a0 * b3;
            acc[1][0] += a1 * b0; acc[1][1] += a1 * b1; acc[1][2] += a1 * b2; acc[1][3] += a1 * b3;
            acc[2][0] += a2 * b0; acc[2][1] += a2 * b1; acc[2][2] += a2 * b2; acc[2][3] += a2 * b3;
            acc[3][0] += a3 * b0; acc[3][1] += a3 * b1; acc[3][2] += a3 * b2; acc[3][3] += a3 * b3;
        }
        __syncthreads();
    }
    #pragma unroll
    for (int i2 = 0; i2 < 4; ++i2) {
        #pragma unroll
        for (int j2 = 0; j2 < 4; ++j2) {
            int m = m0 + ty * 4 + i2, n = n0 + tx * 4 + j2;
            Y[(size_t)m * 512 + n] = acc[i2][j2] + bias[n];
        }
    }
}

// ---------------------------------------------------------------------------
// Kernel 2: attention scores for one batch b.
// S[h,i,j] = ((q+u).k + (q+v).Rp[j-i+512]) / 8, masked to -1e15 for j>=slen
// block: 256 threads, one (h, 32x32 i-j tile).
// ---------------------------------------------------------------------------
__global__ __launch_bounds__(256) void scores_kernel(
    const float* __restrict__ Qb, const float* __restrict__ Kb,
    const float* __restrict__ Rp, const float* __restrict__ u,
    const float* __restrict__ v, const int* __restrict__ seq_len,
    float* __restrict__ S, int b)
{
    const int h  = blockIdx.z;
    const int i0 = blockIdx.y * 32;
    const int j0 = blockIdx.x * 32;

    __shared__ float qus[32][65];
    __shared__ float qvs[32][65];
    __shared__ float ks [32][65];
    __shared__ float rs [63][65];

    const int tid = threadIdx.x;
    {   // load qu/qv/k tiles: 32 rows x 64 cols, 8 floats per thread
        int row = tid >> 3;            // 0..31
        int c   = (tid & 7) * 8;       // 0..56
        const float* qrow = &Qb[(size_t)(b * Ln + i0 + row) * 512 + h * 64];
        const float* krow = &Kb[(size_t)(b * Ln + j0 + row) * 512 + h * 64];
        float4 q1 = *(const float4*)(qrow + c);
        float4 q2 = *(const float4*)(qrow + c + 4);
        float4 k1 = *(const float4*)(krow + c);
        float4 k2 = *(const float4*)(krow + c + 4);
        float4 u1 = *(const float4*)(&u[h * 64 + c]);
        float4 u2 = *(const float4*)(&u[h * 64 + c + 4]);
        float4 v1 = *(const float4*)(&v[h * 64 + c]);
        float4 v2 = *(const float4*)(&v[h * 64 + c + 4]);
        qus[row][c + 0] = q1.x + u1.x; qus[row][c + 1] = q1.y + u1.y;
        qus[row][c + 2] = q1.z + u1.z; qus[row][c + 3] = q1.w + u1.w;
        qus[row][c + 4] = q2.x + u2.x; qus[row][c + 5] = q2.y + u2.y;
        qus[row][c + 6] = q2.z + u2.z; qus[row][c + 7] = q2.w + u2.w;
        qvs[row][c + 0] = q1.x + v1.x; qvs[row][c + 1] = q1.y + v1.y;
        qvs[row][c + 2] = q1.z + v1.z; qvs[row][c + 3] = q1.w + v1.w;
        qvs[row][c + 4] = q2.x + v2.x; qvs[row][c + 5] = q2.y + v2.y;
        qvs[row][c + 6] = q2.z + v2.z; qvs[row][c + 7] = q2.w + v2.w;
        ks[row][c + 0] = k1.x; ks[row][c + 1] = k1.y;
        ks[row][c + 2] = k1.z; ks[row][c + 3] = k1.w;
        ks[row][c + 4] = k2.x; ks[row][c + 5] = k2.y;
        ks[row][c + 6] = k2.z; ks[row][c + 7] = k2.w;
    }
    // load Rp band: rows d = j - i + 512, dd = (j-i)-(j0-i0)+31 in [0,63)
    const int dmin = j0 - i0 + 481;   // in [1, 961]
    for (int idx = tid; idx < 63 * 16; idx += 256) {
        int row = idx >> 4, c4 = (idx & 15) * 4;
        float4 rv = *(const float4*)(&Rp[(size_t)(dmin + row) * 512 + h * 64 + c4]);
        rs[row][c4 + 0] = rv.x; rs[row][c4 + 1] = rv.y;
        rs[row][c4 + 2] = rv.z; rs[row][c4 + 3] = rv.w;
    }
    __syncthreads();

    const int tx = tid & 15, ty = tid >> 4;
    const int ii0 = ty * 2, jj0 = tx * 2;
    const int r00 = jj0 - ii0 + 31;   // dd for (ii0,jj0); (ii0+1,jj0+1) shares it
    float acc00 = 0.f, acc01 = 0.f, acc10 = 0.f, acc11 = 0.f;
    #pragma unroll 8
    for (int d = 0; d < 64; ++d) {
        float a0 = qus[ii0][d],     a1 = qus[ii0 + 1][d];
        float w0 = qvs[ii0][d],     w1 = qvs[ii0 + 1][d];
        float kk0 = ks[jj0][d],     kk1 = ks[jj0 + 1][d];
        float rA = rs[r00][d];
        float rB = rs[r00 + 1][d];
        float rC = rs[r00 - 1][d];
        acc00 += a0 * kk0 + w0 * rA;
        acc01 += a0 * kk1 + w0 * rB;
        acc10 += a1 * kk0 + w1 * rC;
        acc11 += a1 * kk1 + w1 * rA;
    }

    const int slen = seq_len[b];
    const float sc = 0.125f;  // 1/sqrt(64)
    float vals[2][2] = {{acc00 * sc, acc01 * sc}, {acc10 * sc, acc11 * sc}};
    #pragma unroll
    for (int a = 0; a < 2; ++a) {
        #pragma unroll
        for (int bb = 0; bb < 2; ++bb) {
            int i = i0 + ii0 + a, j = j0 + jj0 + bb;
            float val = (j >= slen) ? -1e15f : vals[a][bb];
            S[(size_t)(h * Ln + i) * Ln + j] = val;
        }
    }
}

// ---------------------------------------------------------------------------
// Kernel 3: softmax over j (512) per row; one wave per row, 4 rows/block.
// ---------------------------------------------------------------------------
__global__ __launch_bounds__(256) void softmax_kernel(float* __restrict__ S)
{
    const int row  = blockIdx.x * 4 + (threadIdx.x >> 6);   // 0..NH*L-1
    const int lane = threadIdx.x & 63;
    float* p = &S[(size_t)row * 512];
    float x[8];
    float m = -INFINITY;
    #pragma unroll
    for (int e = 0; e < 8; ++e) { x[e] = p[lane + e * 64]; m = fmaxf(m, x[e]); }
    #pragma unroll
    for (int off = 32; off >= 1; off >>= 1) m = fmaxf(m, __shfl_xor(m, off, 64));
    float s = 0.f;
    #pragma unroll
    for (int e = 0; e < 8; ++e) { x[e] = __expf(x[e] - m); s += x[e]; }
    #pragma unroll
    for (int off = 32; off >= 1; off >>= 1) s += __shfl_xor(s, off, 64);
    const float inv = 1.0f / s;
    #pragma unroll
    for (int e = 0; e < 8; ++e) p[lane + e * 64] = x[e] * inv;
}

// ---------------------------------------------------------------------------
// Kernel 4: O[b,i,h*64+d] = sum_j P[h,i,j] * V[b,j,h*64+d]  (one batch b)
// block: (64-row i-tile, head h); 64x64 out tile, 4x4 per thread.
// ---------------------------------------------------------------------------
__global__ __launch_bounds__(256) void pv_kernel(
    const float* __restrict__ S, const float* __restrict__ Vb,
    float* __restrict__ O, int b)
{
    const int h  = blockIdx.y;
    const int i0 = blockIdx.x * 64;

    __shared__ float Ps[64][65];
    __shared__ float Vs[64][65];

    const int tid = threadIdx.x;
    const int tx = tid & 15, ty = tid >> 4;
    const int lrow = tid >> 2;      // 0..63
    const int lq   = tid & 3;       // 0..3

    float acc[4][4] = {};

    for (int j0 = 0; j0 < 512; j0 += 64) {
        #pragma unroll
        for (int q = 0; q < 4; ++q) {
            int col = (lq + q * 4) * 4;  // 0..60
            float4 pv4 = *(const float4*)(&S[(size_t)(h * Ln + i0 + lrow) * Ln + j0 + col]);
            Ps[lrow][col + 0] = pv4.x; Ps[lrow][col + 1] = pv4.y;
            Ps[lrow][col + 2] = pv4.z; Ps[lrow][col + 3] = pv4.w;
            float4 vv4 = *(const float4*)(&Vb[(size_t)(b * Ln + j0 + lrow) * 512 + h * 64 + col]);
            Vs[lrow][col + 0] = vv4.x; Vs[lrow][col + 1] = vv4.y;
            Vs[lrow][col + 2] = vv4.z; Vs[lrow][col + 3] = vv4.w;
        }
        __syncthreads();
        #pragma unroll
        for (int k = 0; k < 64; ++k) {
            float a0 = Ps[ty * 4 + 0][k], a1 = Ps[ty * 4 + 1][k];
            float a2 = Ps[ty * 4 + 2][k], a3 = Ps[ty * 4 + 3][k];
            float b0 = Vs[k][tx * 4 + 0], b1 = Vs[k][tx * 4 + 1];
            float b2 = Vs[k][tx * 4 + 2], b3 = Vs[k][tx * 4 + 3];
            acc[0][0] += a0 * b0; acc[0][1] += a0 * b1; acc[0][2] += a0 * b2; acc[0][3] += a0 * b3;
            acc[1][0] += a1 * b0; acc[1][1] += a1 * b1; acc[1][2] += a1 * b2; acc[1][3] += a1 * b3;
            acc[2][0] += a2 * b0; acc[2][1] += a2 * b1; acc[2][2] += a2 * b2; acc[2][3] += a2 * b3;
            acc[3][0] += a3 * b0; acc[3][1] += a3 * b1; acc[3][2] += a3 * b2; acc[3][3] += a3 * b3;
        }
        __syncthreads();
    }
    #pragma unroll
    for (int i2 = 0; i2 < 4; ++i2) {
        #pragma unroll
        for (int j2 = 0; j2 < 4; ++j2) {
            O[(size_t)(b * Ln + i0 + ty * 4 + i2) * 512 + h * 64 + tx * 4 + j2] = acc[i2][j2];
        }
    }
}

// ---------------------------------------------------------------------------
// Kernel 5: residual + LayerNorm + exact GELU. One wave per 512-elem row.
// ---------------------------------------------------------------------------
__global__ __launch_bounds__(256) void ln_gelu_kernel(
    const float* __restrict__ src, const float* __restrict__ O,
    const float* __restrict__ gamma, const float* __restrict__ beta,
    float* __restrict__ out)
{
    const int row  = blockIdx.x * 4 + (threadIdx.x >> 6);   // 0..B*L-1
    const int lane = threadIdx.x & 63;
    const float* s = &src[(size_t)row * 512];
    const float* o = &O[(size_t)row * 512];
    float x[8];
    float sum = 0.f;
    #pragma unroll
    for (int e = 0; e < 8; ++e) {
        x[e] = s[lane + e * 64] + o[lane + e * 64];
        sum += x[e];
    }
    #pragma unroll
    for (int off = 32; off >= 1; off >>= 1) sum += __shfl_xor(sum, off, 64);
    const float mean = sum * (1.0f / 512.0f);
    float var = 0.f;
    #pragma unroll
    for (int e = 0; e < 8; ++e) { float d = x[e] - mean; var += d * d; }
    #pragma unroll
    for (int off = 32; off >= 1; off >>= 1) var += __shfl_xor(var, off, 64);
    var *= (1.0f / 512.0f);
    const float inv = rsqrtf(var + 1e-5f);
    #pragma unroll
    for (int e = 0; e < 8; ++e) {
        int c = lane + e * 64;
        float ln = (x[e] - mean) * inv * gamma[c] + beta[c];
        out[(size_t)row * 512 + c] = 0.5f * ln * (1.0f + erff(ln * 0.70710678118654752f));
    }
}

// ---------------------------------------------------------------------------
extern "C" void kernel_launch(void* const* d_in, const int* in_sizes, int n_in,
                              void* d_out, int out_size, void* d_ws, size_t ws_size,
                              hipStream_t stream)
{
    const float* src     = (const float*)d_in[0];
    const int*   seq_len = (const int*)  d_in[1];
    const float* pe      = (const float*)d_in[2];
    const float* Wq      = (const float*)d_in[3];
    const float* bq      = (const float*)d_in[4];
    const float* Wk      = (const float*)d_in[5];
    const float* bk      = (const float*)d_in[6];
    const float* Wv      = (const float*)d_in[7];
    const float* bv      = (const float*)d_in[8];
    const float* Wr      = (const float*)d_in[9];
    const float* br      = (const float*)d_in[10];
    const float* u       = (const float*)d_in[11];
    const float* v       = (const float*)d_in[12];
    const float* gamma   = (const float*)d_in[13];
    const float* beta    = (const float*)d_in[14];
    float* out = (float*)d_out;

    // workspace layout (floats)
    float* ws = (float*)d_ws;
    float* Qb = ws;                       // 4096*512
    float* Kb = ws + 2097152;             // 4096*512
    float* Vb = ws + 4194304;             // 4096*512
    float* Rp = ws + 6291456;             // 1024*512
    float* S  = ws + 6815744;             // NH*L*L (reused per batch)
    float* O  = ws + 8912896;             // 4096*512
    // total: 11,010,048 floats = 42 MiB

    proj_kernel<<<dim3(8, 64, 4), 256, 0, stream>>>(
        src, pe, Wq, bq, Wk, bk, Wv, bv, Wr, br, Qb, Kb, Vb, Rp);

    for (int b = 0; b < Bn; ++b) {
        scores_kernel<<<dim3(16, 16, NHn), 256, 0, stream>>>(Qb, Kb, Rp, u, v, seq_len, S, b);
        softmax_kernel<<<dim3(NHn * Ln / 4), 256, 0, stream>>>(S);
        pv_kernel<<<dim3(Ln / 64, NHn), 256, 0, stream>>>(S, Vb, O, b);
    }

    ln_gelu_kernel<<<dim3(Bn * Ln / 4), 256, 0, stream>>>(src, O, gamma, beta, out);
}

// Round 2
// 330.151 us; speedup vs baseline: 2.1744x; 2.1744x over previous
//
#include <hip/hip_runtime.h>
#include <math.h>

// Problem constants: B=8, L=512, H=512, NH=8, DH=64
#define Bn 8
#define Ln 512
#define Hn 512
#define NHn 8
#define DHn 64

typedef __attribute__((ext_vector_type(8))) short short8;
typedef __attribute__((ext_vector_type(4))) float f32x4;

// fp32 -> bf16 (RNE)
__device__ __forceinline__ unsigned short f2bf(float f) {
    unsigned int u = __float_as_uint(f);
    unsigned int r = (u + 0x7FFFu + ((u >> 16) & 1u)) >> 16;
    return (unsigned short)r;
}

// async global->LDS, 16 bytes per lane. LDS dest must be uniform_base + lane*16.
__device__ __forceinline__ void gload_lds16(const void* g, void* l) {
    __builtin_amdgcn_global_load_lds(
        (const __attribute__((address_space(1))) unsigned int*)g,
        (__attribute__((address_space(3))) unsigned int*)l,
        16, 0, 0);
}

// ---------------------------------------------------------------------------
// Kernel 0: dtype conversions. z selects job.
//  z=0 src->src_bf (2097152), z=1 pe->pe_bf (524288),
//  z=2 Wq->Wcat[0], z=3 Wk->Wcat[262144], z=4 Wv->Wcat[524288],
//  z=5 Wr->Wr_bf, z=6 bias concat (fp32 copy, 1536)
// ---------------------------------------------------------------------------
__global__ __launch_bounds__(256) void convert_kernel(
    const float* __restrict__ src, const float* __restrict__ pe,
    const float* __restrict__ Wq, const float* __restrict__ Wk,
    const float* __restrict__ Wv, const float* __restrict__ Wr,
    const float* __restrict__ bq, const float* __restrict__ bk,
    const float* __restrict__ bv,
    unsigned short* __restrict__ src_bf, unsigned short* __restrict__ pe_bf,
    unsigned short* __restrict__ Wcat_bf, unsigned short* __restrict__ Wr_bf,
    float* __restrict__ bcat)
{
    const int z = blockIdx.y;
    const int idx = blockIdx.x * 256 + threadIdx.x;
    if (z == 6) {
        if (idx < 512)            bcat[idx] = bq[idx];
        else if (idx < 1024)      bcat[idx] = bk[idx - 512];
        else if (idx < 1536)      bcat[idx] = bv[idx - 1024];
        return;
    }
    const float* in; unsigned short* out; int n;
    switch (z) {
      case 0: in = src; out = src_bf;          n = 2097152; break;
      case 1: in = pe;  out = pe_bf;           n = 524288;  break;
      case 2: in = Wq;  out = Wcat_bf;         n = 262144;  break;
      case 3: in = Wk;  out = Wcat_bf + 262144; n = 262144; break;
      case 4: in = Wv;  out = Wcat_bf + 524288; n = 262144; break;
      default: in = Wr; out = Wr_bf;           n = 262144;  break;
    }
    const int i4 = idx * 4;
    if (i4 >= n) return;
    float4 x = *(const float4*)&in[i4];
    ushort4 o;
    o.x = f2bf(x.x); o.y = f2bf(x.y); o.z = f2bf(x.z); o.w = f2bf(x.w);
    *(ushort4*)&out[i4] = o;
}

// ---------------------------------------------------------------------------
// Kernel 1: bf16 MFMA NT-GEMM: C[m][n] = sum_k A[m][k]*B[n][k] + bias[n]
// A: [M,512] bf16 row-major, B: [N,512] bf16 row-major, C fp32 with stride ldc.
// 128x128 tile, BK=32, 256 threads (4 waves, 2x2 wave grid, 64x64 per wave),
// global_load_lds width-16 staging (m97 structure).
// ---------------------------------------------------------------------------
__global__ __launch_bounds__(256) void mfma_nt_kernel(
    const unsigned short* __restrict__ A, const unsigned short* __restrict__ B,
    const float* __restrict__ bias, float* __restrict__ C, int ldc)
{
    __shared__ unsigned short As[128 * 32];
    __shared__ unsigned short Bs[128 * 32];

    const int m0 = blockIdx.y * 128;
    const int n0 = blockIdx.x * 128;
    const int t = threadIdx.x;
    const int wave = t >> 6, lane = t & 63;
    const int wm = (wave >> 1) * 64;   // wave's m-offset in tile
    const int wn = (wave & 1) * 64;    // wave's n-offset in tile

    f32x4 acc[4][4] = {};

    // staging addresses: wave w stages rows [w*32, w*32+32) of each 128x32 tile
    const int srow = wave * 32 + (lane >> 2);   // +0 and +16 for the two insts
    const int scol = (lane & 3) * 8;            // bf16 elems, 16B per lane
    const unsigned short* Ag = A + (size_t)(m0 + srow) * 512 + scol;
    const unsigned short* Bg = B + (size_t)(n0 + srow) * 512 + scol;
    unsigned short* AsW = &As[srow * 32 + scol];
    unsigned short* BsW = &Bs[srow * 32 + scol];

    for (int k0 = 0; k0 < 512; k0 += 32) {
        __syncthreads();   // previous compute done before LDS overwrite
        gload_lds16(Ag + k0,             AsW);
        gload_lds16(Ag + k0 + 16 * 512,  AsW + 16 * 32);
        gload_lds16(Bg + k0,             BsW);
        gload_lds16(Bg + k0 + 16 * 512,  BsW + 16 * 32);
        __syncthreads();   // drains vmcnt (global_load_lds) per compiler barrier semantics

        short8 af[4], bf[4];
        #pragma unroll
        for (int mt = 0; mt < 4; ++mt)
            af[mt] = *(const short8*)&As[(wm + mt * 16 + (lane & 15)) * 32 + (lane >> 4) * 8];
        #pragma unroll
        for (int nt = 0; nt < 4; ++nt)
            bf[nt] = *(const short8*)&Bs[(wn + nt * 16 + (lane & 15)) * 32 + (lane >> 4) * 8];
        #pragma unroll
        for (int mt = 0; mt < 4; ++mt)
            #pragma unroll
            for (int nt = 0; nt < 4; ++nt)
                acc[mt][nt] = __builtin_amdgcn_mfma_f32_16x16x32_bf16(
                    af[mt], bf[nt], acc[mt][nt], 0, 0, 0);
    }

    // C/D layout: col = lane&15, row = (lane>>4)*4 + reg
    const int crow = (lane >> 4) * 4;
    const int ccol = lane & 15;
    #pragma unroll
    for (int mt = 0; mt < 4; ++mt)
        #pragma unroll
        for (int nt = 0; nt < 4; ++nt) {
            const int n = n0 + wn + nt * 16 + ccol;
            const float bn = bias[n];
            #pragma unroll
            for (int r = 0; r < 4; ++r) {
                const int m = m0 + wm + mt * 16 + crow + r;
                C[(size_t)m * ldc + n] = acc[mt][nt][r] + bn;
            }
        }
}

// ---------------------------------------------------------------------------
// Kernel 2: fused flash-style relative-position attention (fp32 compute).
// One block = (b, h, 64-row i-tile). Online softmax; no S materialization.
// S[i,j] = ((q_i+u)·k_j + (q_i+v)·Rp[j-i+512]) / 8, key mask j>=slen -> -1e15.
// ---------------------------------------------------------------------------
__global__ __launch_bounds__(256) void attn_kernel(
    const float* __restrict__ QKV,   // [4096][1536]: q|k|v
    const float* __restrict__ Rp,    // [1024][512]
    const float* __restrict__ u, const float* __restrict__ v,
    const int* __restrict__ seq_len, float* __restrict__ O)
{
    const int i0 = blockIdx.x * 64;
    const int h  = blockIdx.y;
    const int b  = blockIdx.z;
    const int slen = seq_len[b];

    __shared__ float qus[64][68];   // (q+u)[i][d]
    __shared__ float qvs[64][68];   // (q+v)[i][d]
    __shared__ float kst[64][68];   // K transposed: [d][j]
    __shared__ float vsm[64][68];   // V: [j][dv]
    __shared__ float rs [127][68];  // Rp band: [r][d], r = (j-i)+63 tile-local
    __shared__ float Ps [64][68];   // P tile: [i][j]

    const int t  = threadIdx.x;
    const int tx = t & 15, ty = t >> 4;
    const int tx4 = tx * 4, ty4 = ty * 4;

    // stage qu/qv once per block
    {
        const int il = t >> 2;
        const int c0 = (t & 3) * 16;
        const float* qrow = &QKV[(size_t)(b * 512 + i0 + il) * 1536 + h * 64 + c0];
        const float* up = &u[h * 64 + c0];
        const float* vp = &v[h * 64 + c0];
        #pragma unroll
        for (int e = 0; e < 4; ++e) {
            float4 q  = *(const float4*)(qrow + e * 4);
            float4 uu = *(const float4*)(up + e * 4);
            float4 vv = *(const float4*)(vp + e * 4);
            *(float4*)&qus[il][c0 + e * 4] = make_float4(q.x + uu.x, q.y + uu.y, q.z + uu.z, q.w + uu.w);
            *(float4*)&qvs[il][c0 + e * 4] = make_float4(q.x + vv.x, q.y + vv.y, q.z + vv.z, q.w + vv.w);
        }
    }

    float m_run[4], l_run[4], oacc[4][4];
    #pragma unroll
    for (int a = 0; a < 4; ++a) {
        m_run[a] = -3.0e38f; l_run[a] = 0.f;
        #pragma unroll
        for (int c = 0; c < 4; ++c) oacc[a][c] = 0.f;
    }

    for (int j0 = 0; j0 < 512; j0 += 64) {
        __syncthreads();   // protect LDS (incl. first-iter qu staging, prev-iter PV reads)

        // stage K (transposed), V, Rp band
        {
            const int jl = t >> 2;
            const int c0 = (t & 3) * 16;
            const float* base = &QKV[(size_t)(b * 512 + j0 + jl) * 1536 + h * 64];
            const float* krow = base + 512 + c0;
            const float* vrow = base + 1024 + c0;
            #pragma unroll
            for (int e = 0; e < 4; ++e) {
                float4 kk = *(const float4*)(krow + e * 4);
                kst[c0 + e * 4 + 0][jl] = kk.x;
                kst[c0 + e * 4 + 1][jl] = kk.y;
                kst[c0 + e * 4 + 2][jl] = kk.z;
                kst[c0 + e * 4 + 3][jl] = kk.w;
                *(float4*)&vsm[jl][c0 + e * 4] = *(const float4*)(vrow + e * 4);
            }
            const int dmin = j0 - i0 + 449;   // in [1, 897]
            for (int idx = t; idx < 127 * 16; idx += 256) {
                const int r = idx >> 4, c4 = (idx & 15) * 4;
                *(float4*)&rs[r][c4] = *(const float4*)&Rp[(size_t)(dmin + r) * 512 + h * 64 + c4];
            }
        }
        __syncthreads();

        // ---- S tile: 4x4 per thread, i = ty4+a, j = tx4+jb ----
        float acc[4][4] = {};
        const int r0 = 4 * (tx - ty) + 60;   // rows r0..r0+6 in [0,126]
        for (int dc = 0; dc < 64; dc += 4) {
            float qa[4][4], wa[4][4], kbv[4][4], rrv[7][4];
            #pragma unroll
            for (int a = 0; a < 4; ++a) {
                float4 t1 = *(const float4*)&qus[ty4 + a][dc];
                qa[a][0] = t1.x; qa[a][1] = t1.y; qa[a][2] = t1.z; qa[a][3] = t1.w;
                float4 t2 = *(const float4*)&qvs[ty4 + a][dc];
                wa[a][0] = t2.x; wa[a][1] = t2.y; wa[a][2] = t2.z; wa[a][3] = t2.w;
                float4 t3 = *(const float4*)&kst[dc + a][tx4];
                kbv[a][0] = t3.x; kbv[a][1] = t3.y; kbv[a][2] = t3.z; kbv[a][3] = t3.w;
            }
            #pragma unroll
            for (int z = 0; z < 7; ++z) {
                float4 t4 = *(const float4*)&rs[r0 + z][dc];
                rrv[z][0] = t4.x; rrv[z][1] = t4.y; rrv[z][2] = t4.z; rrv[z][3] = t4.w;
            }
            #pragma unroll
            for (int a = 0; a < 4; ++a)
                #pragma unroll
                for (int jb = 0; jb < 4; ++jb) {
                    float s = 0.f;
                    #pragma unroll
                    for (int e = 0; e < 4; ++e)
                        s += qa[a][e] * kbv[e][jb] + wa[a][e] * rrv[3 + jb - a][e];
                    acc[a][jb] += s;
                }
        }

        // ---- scale, mask, online softmax ----
        float alpha[4], tsum[4];
        #pragma unroll
        for (int a = 0; a < 4; ++a) {
            #pragma unroll
            for (int jb = 0; jb < 4; ++jb) {
                float sv = acc[a][jb] * 0.125f;
                if (j0 + tx4 + jb >= slen) sv = -1e15f;
                acc[a][jb] = sv;
            }
            float tm = fmaxf(fmaxf(acc[a][0], acc[a][1]), fmaxf(acc[a][2], acc[a][3]));
            tm = fmaxf(tm, __shfl_xor(tm, 1, 64));
            tm = fmaxf(tm, __shfl_xor(tm, 2, 64));
            tm = fmaxf(tm, __shfl_xor(tm, 4, 64));
            tm = fmaxf(tm, __shfl_xor(tm, 8, 64));
            const float mnew = fmaxf(m_run[a], tm);
            alpha[a] = __expf(m_run[a] - mnew);
            m_run[a] = mnew;
            float s = 0.f;
            #pragma unroll
            for (int jb = 0; jb < 4; ++jb) {
                acc[a][jb] = __expf(acc[a][jb] - mnew);
                s += acc[a][jb];
            }
            s += __shfl_xor(s, 1, 64);
            s += __shfl_xor(s, 2, 64);
            s += __shfl_xor(s, 4, 64);
            s += __shfl_xor(s, 8, 64);
            tsum[a] = s;
            l_run[a] = l_run[a] * alpha[a] + tsum[a];
            // write P row chunk
            *(float4*)&Ps[ty4 + a][tx4] = make_float4(acc[a][0], acc[a][1], acc[a][2], acc[a][3]);
            // rescale O accumulator
            #pragma unroll
            for (int c = 0; c < 4; ++c) oacc[a][c] *= alpha[a];
        }
        __syncthreads();

        // ---- PV: oacc[a][c] += P[i][j] * V[j][dv] ----
        #pragma unroll 4
        for (int j = 0; j < 64; ++j) {
            float vv[4];
            float4 t5 = *(const float4*)&vsm[j][tx4];
            vv[0] = t5.x; vv[1] = t5.y; vv[2] = t5.z; vv[3] = t5.w;
            #pragma unroll
            for (int a = 0; a < 4; ++a) {
                const float p = Ps[ty4 + a][j];
                oacc[a][0] += p * vv[0];
                oacc[a][1] += p * vv[1];
                oacc[a][2] += p * vv[2];
                oacc[a][3] += p * vv[3];
            }
        }
    }

    // epilogue: O = oacc / l
    #pragma unroll
    for (int a = 0; a < 4; ++a) {
        const float inv = 1.0f / l_run[a];
        *(float4*)&O[(size_t)(b * 512 + i0 + ty4 + a) * 512 + h * 64 + tx4] =
            make_float4(oacc[a][0] * inv, oacc[a][1] * inv, oacc[a][2] * inv, oacc[a][3] * inv);
    }
}

// ---------------------------------------------------------------------------
// Kernel 3: residual + LayerNorm + exact GELU. One wave per 512-elem row.
// ---------------------------------------------------------------------------
__global__ __launch_bounds__(256) void ln_gelu_kernel(
    const float* __restrict__ src, const float* __restrict__ O,
    const float* __restrict__ gamma, const float* __restrict__ beta,
    float* __restrict__ out)
{
    const int row  = blockIdx.x * 4 + (threadIdx.x >> 6);
    const int lane = threadIdx.x & 63;
    const float* s = &src[(size_t)row * 512];
    const float* o = &O[(size_t)row * 512];
    float x[8];
    float sum = 0.f;
    #pragma unroll
    for (int e = 0; e < 8; ++e) {
        x[e] = s[lane + e * 64] + o[lane + e * 64];
        sum += x[e];
    }
    #pragma unroll
    for (int off = 32; off >= 1; off >>= 1) sum += __shfl_xor(sum, off, 64);
    const float mean = sum * (1.0f / 512.0f);
    float var = 0.f;
    #pragma unroll
    for (int e = 0; e < 8; ++e) { float d = x[e] - mean; var += d * d; }
    #pragma unroll
    for (int off = 32; off >= 1; off >>= 1) var += __shfl_xor(var, off, 64);
    var *= (1.0f / 512.0f);
    const float inv = rsqrtf(var + 1e-5f);
    #pragma unroll
    for (int e = 0; e < 8; ++e) {
        const int c = lane + e * 64;
        float ln = (x[e] - mean) * inv * gamma[c] + beta[c];
        out[(size_t)row * 512 + c] = 0.5f * ln * (1.0f + erff(ln * 0.70710678118654752f));
    }
}

// ---------------------------------------------------------------------------
extern "C" void kernel_launch(void* const* d_in, const int* in_sizes, int n_in,
                              void* d_out, int out_size, void* d_ws, size_t ws_size,
                              hipStream_t stream)
{
    const float* src     = (const float*)d_in[0];
    const int*   seq_len = (const int*)  d_in[1];
    const float* pe      = (const float*)d_in[2];
    const float* Wq      = (const float*)d_in[3];
    const float* bq      = (const float*)d_in[4];
    const float* Wk      = (const float*)d_in[5];
    const float* bk      = (const float*)d_in[6];
    const float* Wv      = (const float*)d_in[7];
    const float* bv      = (const float*)d_in[8];
    const float* Wr      = (const float*)d_in[9];
    const float* br      = (const float*)d_in[10];
    const float* u       = (const float*)d_in[11];
    const float* v       = (const float*)d_in[12];
    const float* gamma   = (const float*)d_in[13];
    const float* beta    = (const float*)d_in[14];
    float* out = (float*)d_out;

    // workspace layout (byte offsets, all 16B-aligned)
    char* w = (char*)d_ws;
    float*          QKV     = (float*)(w);                      // 4096*1536*4 = 25165824
    float*          Rp      = (float*)(w + 25165824);           // 1024*512*4  =  2097152
    float*          O       = (float*)(w + 27262976);           // 4096*512*4  =  8388608
    unsigned short* src_bf  = (unsigned short*)(w + 35651584);  // 2097152*2   =  4194304
    unsigned short* pe_bf   = (unsigned short*)(w + 39845888);  //  524288*2   =  1048576
    unsigned short* Wcat_bf = (unsigned short*)(w + 40894464);  //  786432*2   =  1572864
    unsigned short* Wr_bf   = (unsigned short*)(w + 42467328);  //  262144*2   =   524288
    float*          bcat    = (float*)(w + 42991616);           //    1536*4   =     6144
    // total ~43.0 MB

    convert_kernel<<<dim3(2048, 7), 256, 0, stream>>>(
        src, pe, Wq, Wk, Wv, Wr, bq, bk, bv,
        src_bf, pe_bf, Wcat_bf, Wr_bf, bcat);

    // QKV = src @ [Wq|Wk|Wv]^T + [bq|bk|bv] : M=4096, N=1536
    mfma_nt_kernel<<<dim3(12, 32), 256, 0, stream>>>(src_bf, Wcat_bf, bcat, QKV, 1536);
    // Rp = pe @ Wr^T + br : M=1024, N=512
    mfma_nt_kernel<<<dim3(4, 8), 256, 0, stream>>>(pe_bf, Wr_bf, br, Rp, 512);

    attn_kernel<<<dim3(8, NHn, Bn), 256, 0, stream>>>(QKV, Rp, u, v, seq_len, O);

    ln_gelu_kernel<<<dim3(Bn * Ln / 4), 256, 0, stream>>>(src, O, gamma, beta, out);
}

// Round 3
// 145.735 us; speedup vs baseline: 4.9259x; 2.2654x over previous
//
#include <hip/hip_runtime.h>
#include <math.h>

// Problem constants: B=8, L=512, H=512, NH=8, DH=64
#define Bn 8
#define Ln 512
#define Hn 512
#define NHn 8
#define DHn 64

typedef __attribute__((ext_vector_type(8))) short short8;
typedef __attribute__((ext_vector_type(4))) float f32x4;

// fp32 -> bf16 (RNE)
__device__ __forceinline__ unsigned short f2bf(float f) {
    unsigned int u = __float_as_uint(f);
    unsigned int r = (u + 0x7FFFu + ((u >> 16) & 1u)) >> 16;
    return (unsigned short)r;
}
__device__ __forceinline__ float bf2f(unsigned short s) {
    return __uint_as_float(((unsigned int)s) << 16);
}

// async global->LDS, 16 bytes per lane (wave-uniform base + lane*16 order).
__device__ __forceinline__ void gload_lds16(const void* g, void* l) {
    __builtin_amdgcn_global_load_lds(
        (const __attribute__((address_space(1))) unsigned int*)g,
        (__attribute__((address_space(3))) unsigned int*)l,
        16, 0, 0);
}

// ---------------------------------------------------------------------------
// Kernel 0: fp32 -> bf16 conversions (flat grid, compact ranges) + bias concat
// ---------------------------------------------------------------------------
__global__ __launch_bounds__(256) void convert_kernel(
    const float* __restrict__ src, const float* __restrict__ pe,
    const float* __restrict__ Wq, const float* __restrict__ Wk,
    const float* __restrict__ Wv, const float* __restrict__ Wr,
    const float* __restrict__ bq, const float* __restrict__ bk,
    const float* __restrict__ bv,
    unsigned short* __restrict__ src_bf, unsigned short* __restrict__ pe_bf,
    unsigned short* __restrict__ Wcat_bf, unsigned short* __restrict__ Wr_bf,
    float* __restrict__ bcat)
{
    const int bid = blockIdx.x;
    const int tid = threadIdx.x;
    const float* in; unsigned short* outp; int base4;
    if (bid < 2048)      { in = src; outp = src_bf;           base4 = bid; }
    else if (bid < 2560) { in = pe;  outp = pe_bf;            base4 = bid - 2048; }
    else if (bid < 2816) { in = Wq;  outp = Wcat_bf;          base4 = bid - 2560; }
    else if (bid < 3072) { in = Wk;  outp = Wcat_bf + 262144; base4 = bid - 2816; }
    else if (bid < 3328) { in = Wv;  outp = Wcat_bf + 524288; base4 = bid - 3072; }
    else if (bid < 3584) { in = Wr;  outp = Wr_bf;            base4 = bid - 3328; }
    else {
        const int idx = (bid - 3584) * 256 + tid;   // 0..1535
        if (idx < 512)            bcat[idx] = bq[idx];
        else if (idx < 1024)      bcat[idx] = bk[idx - 512];
        else if (idx < 1536)      bcat[idx] = bv[idx - 1024];
        return;
    }
    const int i4 = (base4 * 256 + tid) * 4;
    float4 x = *(const float4*)&in[i4];
    ushort4 o;
    o.x = f2bf(x.x); o.y = f2bf(x.y); o.z = f2bf(x.z); o.w = f2bf(x.w);
    *(ushort4*)&outp[i4] = o;
}

// ---------------------------------------------------------------------------
// Kernel 1: bf16 MFMA NT-GEMM, bf16 output: C[m][n] = A[m][:].B[n][:] + bias[n]
// z=0: QKV = src_bf @ Wcat^T + bcat (M=4096,N=1536); z=1: Rp = pe_bf @ Wr^T + br
// 128x128 tile, BK=32, 256 threads, global_load_lds width-16 (m97 structure).
// ---------------------------------------------------------------------------
__global__ __launch_bounds__(256) void mfma_nt_kernel(
    const unsigned short* __restrict__ A0, const unsigned short* __restrict__ B0,
    const float* __restrict__ bias0, unsigned short* __restrict__ C0, int ldc0,
    const unsigned short* __restrict__ A1, const unsigned short* __restrict__ B1,
    const float* __restrict__ bias1, unsigned short* __restrict__ C1, int ldc1)
{
    const unsigned short* A; const unsigned short* B; const float* bias;
    unsigned short* C; int ldc;
    if (blockIdx.z == 0) {
        A = A0; B = B0; bias = bias0; C = C0; ldc = ldc0;
    } else {
        if (blockIdx.x >= 4 || blockIdx.y >= 8) return;  // N=512, M=1024
        A = A1; B = B1; bias = bias1; C = C1; ldc = ldc1;
    }

    __shared__ unsigned short As[128 * 32];
    __shared__ unsigned short Bs[128 * 32];

    const int m0 = blockIdx.y * 128;
    const int n0 = blockIdx.x * 128;
    const int t = threadIdx.x;
    const int wave = t >> 6, lane = t & 63;
    const int wm = (wave >> 1) * 64;
    const int wn = (wave & 1) * 64;

    f32x4 acc[4][4] = {};

    const int srow = wave * 32 + (lane >> 2);
    const int scol = (lane & 3) * 8;
    const unsigned short* Ag = A + (size_t)(m0 + srow) * 512 + scol;
    const unsigned short* Bg = B + (size_t)(n0 + srow) * 512 + scol;
    unsigned short* AsW = &As[srow * 32 + scol];
    unsigned short* BsW = &Bs[srow * 32 + scol];

    for (int k0 = 0; k0 < 512; k0 += 32) {
        __syncthreads();
        gload_lds16(Ag + k0,            AsW);
        gload_lds16(Ag + k0 + 16 * 512, AsW + 16 * 32);
        gload_lds16(Bg + k0,            BsW);
        gload_lds16(Bg + k0 + 16 * 512, BsW + 16 * 32);
        __syncthreads();

        short8 af[4], bf[4];
        #pragma unroll
        for (int mt = 0; mt < 4; ++mt)
            af[mt] = *(const short8*)&As[(wm + mt * 16 + (lane & 15)) * 32 + (lane >> 4) * 8];
        #pragma unroll
        for (int nt = 0; nt < 4; ++nt)
            bf[nt] = *(const short8*)&Bs[(wn + nt * 16 + (lane & 15)) * 32 + (lane >> 4) * 8];
        #pragma unroll
        for (int mt = 0; mt < 4; ++mt)
            #pragma unroll
            for (int nt = 0; nt < 4; ++nt)
                acc[mt][nt] = __builtin_amdgcn_mfma_f32_16x16x32_bf16(
                    af[mt], bf[nt], acc[mt][nt], 0, 0, 0);
    }

    const int crow = (lane >> 4) * 4;
    const int ccol = lane & 15;
    #pragma unroll
    for (int mt = 0; mt < 4; ++mt)
        #pragma unroll
        for (int nt = 0; nt < 4; ++nt) {
            const int n = n0 + wn + nt * 16 + ccol;
            const float bn = bias[n];
            #pragma unroll
            for (int r = 0; r < 4; ++r) {
                const int m = m0 + wm + mt * 16 + crow + r;
                C[(size_t)m * ldc + n] = f2bf(acc[mt][nt][r] + bn);
            }
        }
}

// ---------------------------------------------------------------------------
// Kernel 2: fused flash-style rel-pos attention, bf16 MFMA.
// Block = (b, h, 64-row i-tile), 4 waves x 16-row strips.
// S = ((q+u)·k + (q+v)·Rp[j-i+512]) / 8; Bt via skew-GEMM against a 128-row
// Rp band, gathered per-lane from per-wave-private QR_T LDS.
// ---------------------------------------------------------------------------
#define PADK 72   // bf16 elems per LDS row (stride 144 B, 16B-aligned)
__global__ __launch_bounds__(256) void attn_kernel(
    const unsigned short* __restrict__ QKVb,  // [4096][1536] bf16: q|k|v
    const unsigned short* __restrict__ Rpb,   // [1024][512] bf16
    const float* __restrict__ u, const float* __restrict__ v,
    const int* __restrict__ seq_len, float* __restrict__ O)
{
    const int i0 = blockIdx.x * 64;
    const int h  = blockIdx.y;
    const int b  = blockIdx.z;
    const int slen = seq_len[b];

    __shared__ unsigned short k_s [64 * PADK];    //  9216 B  K[j][d]
    __shared__ unsigned short vT_s[64 * PADK];    //  9216 B  V^T[dv][j]
    __shared__ unsigned short rs_s[128 * PADK];   // 18432 B  Rp band[r][d]
    __shared__ unsigned short p_s [4 * 16 * PADK];// 9216 B   P[i][j] per wave
    __shared__ unsigned short qrT [4 * 128 * 20]; // 20480 B  QR^T[band][i16] per wave
    // total 66,560 B -> 2 blocks/CU

    const int t = threadIdx.x;
    const int wave = t >> 6, lane = t & 63;
    const int l = lane & 15, g = lane >> 4;

    // ---- per-wave A-fragments qu = q+u, qv = q+v (registers, whole j-loop) --
    short8 af_qu[2], af_qv[2];
    {
        const unsigned short* qrow =
            QKVb + (size_t)(b * 512 + i0 + wave * 16 + l) * 1536 + h * 64;
        #pragma unroll
        for (int kk = 0; kk < 2; ++kk) {
            const int c = kk * 32 + g * 8;
            unsigned short q8[8];
            *(uint4*)q8 = *(const uint4*)(qrow + c);
            float4 u0 = *(const float4*)(u + h * 64 + c);
            float4 u1 = *(const float4*)(u + h * 64 + c + 4);
            float4 v0 = *(const float4*)(v + h * 64 + c);
            float4 v1 = *(const float4*)(v + h * 64 + c + 4);
            float uf[8] = {u0.x,u0.y,u0.z,u0.w,u1.x,u1.y,u1.z,u1.w};
            float vf[8] = {v0.x,v0.y,v0.z,v0.w,v1.x,v1.y,v1.z,v1.w};
            short8 qu, qv;
            #pragma unroll
            for (int e = 0; e < 8; ++e) {
                float qf = bf2f(q8[e]);
                qu[e] = (short)f2bf(qf + uf[e]);
                qv[e] = (short)f2bf(qf + vf[e]);
            }
            af_qu[kk] = qu; af_qv[kk] = qv;
        }
    }

    float m_run[4], l_run[4];
    f32x4 accO[4] = {};
    #pragma unroll
    for (int r = 0; r < 4; ++r) { m_run[r] = -3.0e38f; l_run[r] = 0.f; }

    const int dmin = i0 ? (0 - i0 + 449) : 449;   // recomputed per j0 below

    for (int j0 = 0; j0 < 512; j0 += 64) {
        __syncthreads();   // prev-iter MFMA reads done before staging overwrite

        // ---- stage K, V^T (bf16) ----
        {
            const int jr = t >> 2, c0 = (t & 3) * 16;
            const unsigned short* base =
                QKVb + (size_t)(b * 512 + j0 + jr) * 1536 + h * 64;
            uint4 kv0 = *(const uint4*)(base + 512 + c0);
            uint4 kv1 = *(const uint4*)(base + 512 + c0 + 8);
            *(uint4*)(k_s + jr * PADK + c0)     = kv0;
            *(uint4*)(k_s + jr * PADK + c0 + 8) = kv1;
            unsigned short vt[16];
            *(uint4*)vt       = *(const uint4*)(base + 1024 + c0);
            *(uint4*)(vt + 8) = *(const uint4*)(base + 1024 + c0 + 8);
            #pragma unroll
            for (int m = 0; m < 16; ++m)
                vT_s[(c0 + m) * PADK + jr] = vt[m];
        }
        // ---- stage Rp band: band r -> global row (j0 - i0 + 449 + r) ----
        {
            const int r = t >> 1, c0 = (t & 1) * 32;
            int grow = j0 - i0 + 449 + r;
            if (grow > 1023) grow = 1023;   // r=127 never consumed
            const unsigned short* rp = Rpb + (size_t)grow * 512 + h * 64 + c0;
            #pragma unroll
            for (int e = 0; e < 4; ++e)
                *(uint4*)(rs_s + r * PADK + c0 + e * 8) = *(const uint4*)(rp + e * 8);
        }
        __syncthreads();

        // ---- A-term: accA[nt] = qu . K^T  (16x64 per wave) ----
        f32x4 accA[4];
        #pragma unroll
        for (int nt = 0; nt < 4; ++nt) {
            f32x4 a = {};
            #pragma unroll
            for (int kk = 0; kk < 2; ++kk) {
                short8 bk = *(const short8*)&k_s[(nt * 16 + l) * PADK + kk * 32 + g * 8];
                a = __builtin_amdgcn_mfma_f32_16x16x32_bf16(af_qu[kk], bk, a, 0, 0, 0);
            }
            accA[nt] = a;
        }

        // ---- Bt skew-GEMM: QR[i16][band] = qv . rs^T, write to qrT (bf16) ----
        #pragma unroll
        for (int nt8 = 0; nt8 < 8; ++nt8) {
            f32x4 a = {};
            #pragma unroll
            for (int kk = 0; kk < 2; ++kk) {
                short8 br8 = *(const short8*)&rs_s[(nt8 * 16 + l) * PADK + kk * 32 + g * 8];
                a = __builtin_amdgcn_mfma_f32_16x16x32_bf16(af_qv[kk], br8, a, 0, 0, 0);
            }
            ushort4 w4;
            w4.x = f2bf(a[0]); w4.y = f2bf(a[1]); w4.z = f2bf(a[2]); w4.w = f2bf(a[3]);
            *(ushort4*)(qrT + ((size_t)wave * 128 + nt8 * 16 + l) * 20 + g * 4) = w4;
        }
        __builtin_amdgcn_sched_barrier(0);  // keep gather below the QR writes

        // ---- gather + scale + mask -> scores ----
        float sv[4][4];
        #pragma unroll
        for (int nt = 0; nt < 4; ++nt)
            #pragma unroll
            for (int r = 0; r < 4; ++r) {
                const int i16 = g * 4 + r;
                const int band = nt * 16 + l - (wave * 16 + i16) + 63;  // [0,126]
                const float qr = bf2f(qrT[((size_t)wave * 128 + band) * 20 + i16]);
                float s = (accA[nt][r] + qr) * 0.125f;
                if (j0 + nt * 16 + l >= slen) s = -1e15f;
                sv[nt][r] = s;
            }

        // ---- online softmax (rows owned by lanes sharing g) ----
        float alpha_r[4];
        #pragma unroll
        for (int r = 0; r < 4; ++r) {
            float tm = fmaxf(fmaxf(sv[0][r], sv[1][r]), fmaxf(sv[2][r], sv[3][r]));
            tm = fmaxf(tm, __shfl_xor(tm, 1, 64));
            tm = fmaxf(tm, __shfl_xor(tm, 2, 64));
            tm = fmaxf(tm, __shfl_xor(tm, 4, 64));
            tm = fmaxf(tm, __shfl_xor(tm, 8, 64));
            const float mn = fmaxf(m_run[r], tm);
            alpha_r[r] = __expf(m_run[r] - mn);
            m_run[r] = mn;
            float ss = 0.f;
            #pragma unroll
            for (int nt = 0; nt < 4; ++nt) {
                const float p = __expf(sv[nt][r] - mn);
                sv[nt][r] = p; ss += p;
            }
            ss += __shfl_xor(ss, 1, 64);
            ss += __shfl_xor(ss, 2, 64);
            ss += __shfl_xor(ss, 4, 64);
            ss += __shfl_xor(ss, 8, 64);
            l_run[r] = l_run[r] * alpha_r[r] + ss;
        }

        // ---- write P (bf16, per-wave region) ----
        #pragma unroll
        for (int nt = 0; nt < 4; ++nt)
            #pragma unroll
            for (int r = 0; r < 4; ++r)
                p_s[((size_t)wave * 16 + g * 4 + r) * PADK + nt * 16 + l] = f2bf(sv[nt][r]);
        __builtin_amdgcn_sched_barrier(0);  // keep PV reads below P writes

        // ---- rescale O accumulator ----
        #pragma unroll
        for (int nt = 0; nt < 4; ++nt)
            #pragma unroll
            for (int r = 0; r < 4; ++r)
                accO[nt][r] *= alpha_r[r];

        // ---- PV: accO[nt] += P . V ----
        short8 pa[2];
        #pragma unroll
        for (int kk = 0; kk < 2; ++kk)
            pa[kk] = *(const short8*)&p_s[((size_t)wave * 16 + l) * PADK + kk * 32 + g * 8];
        #pragma unroll
        for (int nt = 0; nt < 4; ++nt) {
            #pragma unroll
            for (int kk = 0; kk < 2; ++kk) {
                short8 bv8 = *(const short8*)&vT_s[(nt * 16 + l) * PADK + kk * 32 + g * 8];
                accO[nt] = __builtin_amdgcn_mfma_f32_16x16x32_bf16(pa[kk], bv8, accO[nt], 0, 0, 0);
            }
        }
    }

    // ---- epilogue: O = accO / l ----
    float inv[4];
    #pragma unroll
    for (int r = 0; r < 4; ++r) inv[r] = 1.0f / l_run[r];
    #pragma unroll
    for (int nt = 0; nt < 4; ++nt)
        #pragma unroll
        for (int r = 0; r < 4; ++r)
            O[(size_t)(b * 512 + i0 + wave * 16 + g * 4 + r) * 512 + h * 64 + nt * 16 + l]
                = accO[nt][r] * inv[r];
}

// ---------------------------------------------------------------------------
// Kernel 3: residual + LayerNorm + exact GELU. One wave per 512-elem row.
// ---------------------------------------------------------------------------
__global__ __launch_bounds__(256) void ln_gelu_kernel(
    const float* __restrict__ src, const float* __restrict__ O,
    const float* __restrict__ gamma, const float* __restrict__ beta,
    float* __restrict__ out)
{
    const int row  = blockIdx.x * 4 + (threadIdx.x >> 6);
    const int lane = threadIdx.x & 63;
    const float* s = &src[(size_t)row * 512];
    const float* o = &O[(size_t)row * 512];
    float x[8];
    float sum = 0.f;
    #pragma unroll
    for (int e = 0; e < 8; ++e) {
        x[e] = s[lane + e * 64] + o[lane + e * 64];
        sum += x[e];
    }
    #pragma unroll
    for (int off = 32; off >= 1; off >>= 1) sum += __shfl_xor(sum, off, 64);
    const float mean = sum * (1.0f / 512.0f);
    float var = 0.f;
    #pragma unroll
    for (int e = 0; e < 8; ++e) { float d = x[e] - mean; var += d * d; }
    #pragma unroll
    for (int off = 32; off >= 1; off >>= 1) var += __shfl_xor(var, off, 64);
    var *= (1.0f / 512.0f);
    const float inv = rsqrtf(var + 1e-5f);
    #pragma unroll
    for (int e = 0; e < 8; ++e) {
        const int c = lane + e * 64;
        float ln = (x[e] - mean) * inv * gamma[c] + beta[c];
        out[(size_t)row * 512 + c] = 0.5f * ln * (1.0f + erff(ln * 0.70710678118654752f));
    }
}

// ---------------------------------------------------------------------------
extern "C" void kernel_launch(void* const* d_in, const int* in_sizes, int n_in,
                              void* d_out, int out_size, void* d_ws, size_t ws_size,
                              hipStream_t stream)
{
    const float* src     = (const float*)d_in[0];
    const int*   seq_len = (const int*)  d_in[1];
    const float* pe      = (const float*)d_in[2];
    const float* Wq      = (const float*)d_in[3];
    const float* bq      = (const float*)d_in[4];
    const float* Wk      = (const float*)d_in[5];
    const float* bk      = (const float*)d_in[6];
    const float* Wv      = (const float*)d_in[7];
    const float* bv      = (const float*)d_in[8];
    const float* Wr      = (const float*)d_in[9];
    const float* br      = (const float*)d_in[10];
    const float* u       = (const float*)d_in[11];
    const float* v       = (const float*)d_in[12];
    const float* gamma   = (const float*)d_in[13];
    const float* beta    = (const float*)d_in[14];
    float* out = (float*)d_out;

    // workspace layout (byte offsets, 16B-aligned)
    char* w = (char*)d_ws;
    unsigned short* QKVb    = (unsigned short*)(w);              // 4096*1536*2 = 12582912
    unsigned short* Rpb     = (unsigned short*)(w + 12582912);   // 1024*512*2  =  1048576
    float*          O       = (float*)         (w + 13631488);   // 4096*512*4  =  8388608
    unsigned short* src_bf  = (unsigned short*)(w + 22020096);   // 2097152*2   =  4194304
    unsigned short* pe_bf   = (unsigned short*)(w + 26214400);   //  524288*2   =  1048576
    unsigned short* Wcat_bf = (unsigned short*)(w + 27262976);   //  786432*2   =  1572864
    unsigned short* Wr_bf   = (unsigned short*)(w + 28835840);   //  262144*2   =   524288
    float*          bcat    = (float*)         (w + 29360128);   //    1536*4   =     6144
    // total ~28 MB

    convert_kernel<<<dim3(3590), 256, 0, stream>>>(
        src, pe, Wq, Wk, Wv, Wr, bq, bk, bv,
        src_bf, pe_bf, Wcat_bf, Wr_bf, bcat);

    // z=0: QKV = src @ [Wq|Wk|Wv]^T + bcat (M=4096,N=1536)
    // z=1: Rp  = pe @ Wr^T + br           (M=1024,N=512)
    mfma_nt_kernel<<<dim3(12, 32, 2), 256, 0, stream>>>(
        src_bf, Wcat_bf, bcat, QKVb, 1536,
        pe_bf,  Wr_bf,   br,   Rpb,  512);

    attn_kernel<<<dim3(8, NHn, Bn), 256, 0, stream>>>(QKVb, Rpb, u, v, seq_len, O);

    ln_gelu_kernel<<<dim3(Bn * Ln / 4), 256, 0, stream>>>(src, O, gamma, beta, out);
}

// Round 4
// 142.142 us; speedup vs baseline: 5.0504x; 1.0253x over previous
//
#include <hip/hip_runtime.h>
#include <math.h>

// Problem constants: B=8, L=512, H=512, NH=8, DH=64
#define Bn 8
#define Ln 512
#define Hn 512
#define NHn 8
#define DHn 64

typedef __attribute__((ext_vector_type(8))) short short8;
typedef __attribute__((ext_vector_type(4))) float f32x4;

// fp32 -> bf16 (RNE)
__device__ __forceinline__ unsigned short f2bf(float f) {
    unsigned int u = __float_as_uint(f);
    unsigned int r = (u + 0x7FFFu + ((u >> 16) & 1u)) >> 16;
    return (unsigned short)r;
}
__device__ __forceinline__ float bf2f(unsigned short s) {
    return __uint_as_float(((unsigned int)s) << 16);
}

// async global->LDS, 16 bytes per lane (wave-uniform base + lane*16 order).
__device__ __forceinline__ void gload_lds16(const void* g, void* l) {
    __builtin_amdgcn_global_load_lds(
        (const __attribute__((address_space(1))) unsigned int*)g,
        (__attribute__((address_space(3))) unsigned int*)l,
        16, 0, 0);
}

// ---------------------------------------------------------------------------
// Kernel 0: fp32 -> bf16 conversions (flat grid, compact ranges) + bias concat
// ---------------------------------------------------------------------------
__global__ __launch_bounds__(256) void convert_kernel(
    const float* __restrict__ src, const float* __restrict__ pe,
    const float* __restrict__ Wq, const float* __restrict__ Wk,
    const float* __restrict__ Wv, const float* __restrict__ Wr,
    const float* __restrict__ bq, const float* __restrict__ bk,
    const float* __restrict__ bv,
    unsigned short* __restrict__ src_bf, unsigned short* __restrict__ pe_bf,
    unsigned short* __restrict__ Wcat_bf, unsigned short* __restrict__ Wr_bf,
    float* __restrict__ bcat)
{
    const int bid = blockIdx.x;
    const int tid = threadIdx.x;
    const float* in; unsigned short* outp; int base4;
    if (bid < 2048)      { in = src; outp = src_bf;           base4 = bid; }
    else if (bid < 2560) { in = pe;  outp = pe_bf;            base4 = bid - 2048; }
    else if (bid < 2816) { in = Wq;  outp = Wcat_bf;          base4 = bid - 2560; }
    else if (bid < 3072) { in = Wk;  outp = Wcat_bf + 262144; base4 = bid - 2816; }
    else if (bid < 3328) { in = Wv;  outp = Wcat_bf + 524288; base4 = bid - 3072; }
    else if (bid < 3584) { in = Wr;  outp = Wr_bf;            base4 = bid - 3328; }
    else {
        const int idx = (bid - 3584) * 256 + tid;   // 0..1535
        if (idx < 512)            bcat[idx] = bq[idx];
        else if (idx < 1024)      bcat[idx] = bk[idx - 512];
        else if (idx < 1536)      bcat[idx] = bv[idx - 1024];
        return;
    }
    const int i4 = (base4 * 256 + tid) * 4;
    float4 x = *(const float4*)&in[i4];
    ushort4 o;
    o.x = f2bf(x.x); o.y = f2bf(x.y); o.z = f2bf(x.z); o.w = f2bf(x.w);
    *(ushort4*)&outp[i4] = o;
}

// ---------------------------------------------------------------------------
// Kernel 1: bf16 MFMA NT-GEMM (128x128 tile, BK=32, global_load_lds staging).
// z=0, x<8 : QK[m][n]  = src . Wcat_n  + bcat[n]   (m=4096 rows, n in [0,1024))
// z=0, x>=8: VT[n'][m] = Wcat_{n'+1024} . src_m + bcat[n'+1024]  (operand swap:
//            A = V-weight rows, B = src rows -> C-layout directly yields V^T
//            [dv 512][b*512+j 4096] with coalesced stores)
// z=1      : Rp[m][n]  = pe . Wr_n + br[n]         (M=1024, N=512)
// ---------------------------------------------------------------------------
__global__ __launch_bounds__(256) void mfma_nt_kernel(
    const unsigned short* __restrict__ src_bf,
    const unsigned short* __restrict__ Wcat_bf,
    const float* __restrict__ bcat,
    unsigned short* __restrict__ QKb,   // [4096][1024]
    unsigned short* __restrict__ VTg,   // [512][4096]
    const unsigned short* __restrict__ pe_bf,
    const unsigned short* __restrict__ Wr_bf,
    const float* __restrict__ br,
    unsigned short* __restrict__ Rpb)   // [1024][512]
{
    const unsigned short* A; const unsigned short* B;
    int m0, n0, mode;   // mode 0: QK, 1: VT (swapped), 2: Rp
    if (blockIdx.z == 0) {
        if (blockIdx.x < 8) {
            mode = 0; A = src_bf;  m0 = blockIdx.y * 128;
            B = Wcat_bf; n0 = blockIdx.x * 128;
        } else {
            mode = 1; A = Wcat_bf; m0 = blockIdx.x * 128;   // 1024..1535
            B = src_bf;  n0 = blockIdx.y * 128;
        }
    } else {
        if (blockIdx.x >= 4 || blockIdx.y >= 8) return;
        mode = 2; A = pe_bf; m0 = blockIdx.y * 128;
        B = Wr_bf; n0 = blockIdx.x * 128;
    }

    __shared__ unsigned short As[128 * 32];
    __shared__ unsigned short Bs[128 * 32];

    const int t = threadIdx.x;
    const int wave = t >> 6, lane = t & 63;
    const int wm = (wave >> 1) * 64;
    const int wn = (wave & 1) * 64;

    f32x4 acc[4][4] = {};

    const int srow = wave * 32 + (lane >> 2);
    const int scol = (lane & 3) * 8;
    const unsigned short* Ag = A + (size_t)(m0 + srow) * 512 + scol;
    const unsigned short* Bg = B + (size_t)(n0 + srow) * 512 + scol;
    unsigned short* AsW = &As[srow * 32 + scol];
    unsigned short* BsW = &Bs[srow * 32 + scol];

    for (int k0 = 0; k0 < 512; k0 += 32) {
        __syncthreads();
        gload_lds16(Ag + k0,            AsW);
        gload_lds16(Ag + k0 + 16 * 512, AsW + 16 * 32);
        gload_lds16(Bg + k0,            BsW);
        gload_lds16(Bg + k0 + 16 * 512, BsW + 16 * 32);
        __syncthreads();

        short8 af[4], bf[4];
        #pragma unroll
        for (int mt = 0; mt < 4; ++mt)
            af[mt] = *(const short8*)&As[(wm + mt * 16 + (lane & 15)) * 32 + (lane >> 4) * 8];
        #pragma unroll
        for (int nt = 0; nt < 4; ++nt)
            bf[nt] = *(const short8*)&Bs[(wn + nt * 16 + (lane & 15)) * 32 + (lane >> 4) * 8];
        #pragma unroll
        for (int mt = 0; mt < 4; ++mt)
            #pragma unroll
            for (int nt = 0; nt < 4; ++nt)
                acc[mt][nt] = __builtin_amdgcn_mfma_f32_16x16x32_bf16(
                    af[mt], bf[nt], acc[mt][nt], 0, 0, 0);
    }

    const int crow = (lane >> 4) * 4;
    const int ccol = lane & 15;
    if (mode == 0) {
        #pragma unroll
        for (int mt = 0; mt < 4; ++mt)
            #pragma unroll
            for (int nt = 0; nt < 4; ++nt) {
                const int n = n0 + wn + nt * 16 + ccol;
                const float bn = bcat[n];
                #pragma unroll
                for (int r = 0; r < 4; ++r) {
                    const int m = m0 + wm + mt * 16 + crow + r;
                    QKb[(size_t)m * 1024 + n] = f2bf(acc[mt][nt][r] + bn);
                }
            }
    } else if (mode == 1) {
        #pragma unroll
        for (int mt = 0; mt < 4; ++mt)
            #pragma unroll
            for (int nt = 0; nt < 4; ++nt) {
                const int n = n0 + wn + nt * 16 + ccol;   // src row index
                #pragma unroll
                for (int r = 0; r < 4; ++r) {
                    const int m = m0 + wm + mt * 16 + crow + r;   // 1024..1535
                    VTg[(size_t)(m - 1024) * 4096 + n] = f2bf(acc[mt][nt][r] + bcat[m]);
                }
            }
    } else {
        #pragma unroll
        for (int mt = 0; mt < 4; ++mt)
            #pragma unroll
            for (int nt = 0; nt < 4; ++nt) {
                const int n = n0 + wn + nt * 16 + ccol;
                const float bn = br[n];
                #pragma unroll
                for (int r = 0; r < 4; ++r) {
                    const int m = m0 + wm + mt * 16 + crow + r;
                    Rpb[(size_t)m * 512 + n] = f2bf(acc[mt][nt][r] + bn);
                }
            }
    }
}

// ---------------------------------------------------------------------------
// Kernel 2: fused flash-style rel-pos attention, bf16 MFMA, rolling Bt band.
// Block = (b, h, 64-row i-tile), 4 waves x 16-row strips.
// S = ((q+u)·k + (q+v)·Rp[j-i+512]) / 8. The Bt band term is computed
// incrementally: per j-tile only the 64 NEW band rows (g = j0-i0+512..+575)
// are MFMA'd (4/wave vs 16 before); results live in a block-shared rolling
// qrT[i][slot] buffer keyed by slot = (j-i+512) & 127 (chunks align to
// 64-slot halves since i0,j0 are multiples of 64).
// ---------------------------------------------------------------------------
#define PADK 72    // k_s/vT_s/rs_s/p_s row stride (144 B): 2-way-free banks
#define QRS 133    // qrT i-row stride in ushorts (266 B): gather groups land
                   // on disjoint bank octets ((4*266-8)/4 % 32 == 8)
__global__ __launch_bounds__(256) void attn_kernel(
    const unsigned short* __restrict__ QKb,  // [4096][1024] bf16: q|k
    const unsigned short* __restrict__ VTg,  // [512][4096] bf16 V^T
    const unsigned short* __restrict__ Rpb,  // [1024][512] bf16
    const float* __restrict__ u, const float* __restrict__ v,
    const int* __restrict__ seq_len, float* __restrict__ O)
{
    const int i0 = blockIdx.x * 64;
    const int h  = blockIdx.y;
    const int b  = blockIdx.z;
    const int slen = seq_len[b];

    __shared__ unsigned short k_s [64 * PADK];   // 9216 B  K[j][d]
    __shared__ unsigned short vT_s[64 * PADK];   // 9216 B  V^T[dv][j]
    __shared__ unsigned short rs_s[64 * PADK];   // 9216 B  Rp chunk[rr][d]
    __shared__ unsigned short p_s [64 * PADK];   // 9216 B  P[i][j]
    __shared__ unsigned short qrT [64 * QRS];    // 17024 B QR[i][slot]
    // total 53,888 B -> 3 blocks/CU

    const int t = threadIdx.x;
    const int wave = t >> 6, lane = t & 63;
    const int l = lane & 15, g = lane >> 4;

    // ---- per-wave A-fragments qu = q+u, qv = q+v (registers, whole j-loop) --
    short8 af_qu[2], af_qv[2];
    {
        const unsigned short* qrow =
            QKb + (size_t)(b * 512 + i0 + wave * 16 + l) * 1024 + h * 64;
        #pragma unroll
        for (int kk = 0; kk < 2; ++kk) {
            const int c = kk * 32 + g * 8;
            unsigned short q8[8];
            *(uint4*)q8 = *(const uint4*)(qrow + c);
            float4 u0 = *(const float4*)(u + h * 64 + c);
            float4 u1 = *(const float4*)(u + h * 64 + c + 4);
            float4 v0 = *(const float4*)(v + h * 64 + c);
            float4 v1 = *(const float4*)(v + h * 64 + c + 4);
            float uf[8] = {u0.x,u0.y,u0.z,u0.w,u1.x,u1.y,u1.z,u1.w};
            float vf[8] = {v0.x,v0.y,v0.z,v0.w,v1.x,v1.y,v1.z,v1.w};
            short8 qu, qv;
            #pragma unroll
            for (int e = 0; e < 8; ++e) {
                float qf = bf2f(q8[e]);
                qu[e] = (short)f2bf(qf + uf[e]);
                qv[e] = (short)f2bf(qf + vf[e]);
            }
            af_qu[kk] = qu; af_qv[kk] = qv;
        }
    }

    float m_run[4], l_run[4];
    f32x4 accO[4] = {};
    #pragma unroll
    for (int r = 0; r < 4; ++r) { m_run[r] = -3.0e38f; l_run[r] = 0.f; }

    const int jr = t >> 2, c0 = (t & 3) * 16;   // staging coords (row, 16-col)

    for (int jt = 0; jt < 8; ++jt) {
        const int j0 = jt * 64;
        __syncthreads();   // all prev-tile LDS reads (incl. qrT gathers) done

        // ---- stage K and V^T (uint4 coalesced, no transpose needed) ----
        {
            const unsigned short* kp =
                QKb + (size_t)(b * 512 + j0 + jr) * 1024 + 512 + h * 64 + c0;
            *(uint4*)(k_s + jr * PADK + c0)     = *(const uint4*)(kp);
            *(uint4*)(k_s + jr * PADK + c0 + 8) = *(const uint4*)(kp + 8);
            const unsigned short* vp =
                VTg + (size_t)(h * 64 + jr) * 4096 + b * 512 + j0 + c0;
            *(uint4*)(vT_s + jr * PADK + c0)     = *(const uint4*)(vp);
            *(uint4*)(vT_s + jr * PADK + c0 + 8) = *(const uint4*)(vp + 8);
        }

        // ---- Bt band chunks: compute only NEW bands into rolling qrT ----
        const int nchunk = (jt == 0) ? 2 : 1;
        for (int c = 0; c < nchunk; ++c) {
            const int g_base = (jt == 0) ? (448 - i0 + 64 * c) : (j0 - i0 + 512);
            {   // stage 64 Rp rows [g_base, g_base+64)
                const unsigned short* rp =
                    Rpb + (size_t)(g_base + jr) * 512 + h * 64 + c0;
                *(uint4*)(rs_s + jr * PADK + c0)     = *(const uint4*)(rp);
                *(uint4*)(rs_s + jr * PADK + c0 + 8) = *(const uint4*)(rp + 8);
            }
            __syncthreads();
            const int slot0 = (g_base & 127);
            #pragma unroll
            for (int nt8 = 0; nt8 < 4; ++nt8) {
                f32x4 a = {};
                #pragma unroll
                for (int kk = 0; kk < 2; ++kk) {
                    short8 br8 = *(const short8*)&rs_s[(nt8 * 16 + l) * PADK + kk * 32 + g * 8];
                    a = __builtin_amdgcn_mfma_f32_16x16x32_bf16(af_qv[kk], br8, a, 0, 0, 0);
                }
                const int sl = slot0 + nt8 * 16 + l;
                #pragma unroll
                for (int r = 0; r < 4; ++r)
                    qrT[(wave * 16 + g * 4 + r) * QRS + sl] = f2bf(a[r]);
            }
            if (c + 1 < nchunk) __syncthreads();  // before restaging rs_s
        }
        __syncthreads();   // qrT chunk(s) visible block-wide; k_s/vT_s staged

        // ---- A-term: accA[nt] = qu . K^T  (16x64 per wave) ----
        f32x4 accA[4];
        #pragma unroll
        for (int nt = 0; nt < 4; ++nt) {
            f32x4 a = {};
            #pragma unroll
            for (int kk = 0; kk < 2; ++kk) {
                short8 bk = *(const short8*)&k_s[(nt * 16 + l) * PADK + kk * 32 + g * 8];
                a = __builtin_amdgcn_mfma_f32_16x16x32_bf16(af_qu[kk], bk, a, 0, 0, 0);
            }
            accA[nt] = a;
        }

        // ---- gather rolling band + scale + mask -> scores ----
        float sv[4][4];
        #pragma unroll
        for (int nt = 0; nt < 4; ++nt)
            #pragma unroll
            for (int r = 0; r < 4; ++r) {
                const int il = wave * 16 + g * 4 + r;
                const int slot = (j0 + nt * 16 + l - i0 - il + 512) & 127;
                const float qr = bf2f(qrT[il * QRS + slot]);
                float s = (accA[nt][r] + qr) * 0.125f;
                if (j0 + nt * 16 + l >= slen) s = -1e15f;
                sv[nt][r] = s;
            }

        // ---- online softmax (row r owned by lanes sharing g) ----
        float alpha_r[4];
        #pragma unroll
        for (int r = 0; r < 4; ++r) {
            float tm = fmaxf(fmaxf(sv[0][r], sv[1][r]), fmaxf(sv[2][r], sv[3][r]));
            tm = fmaxf(tm, __shfl_xor(tm, 1, 64));
            tm = fmaxf(tm, __shfl_xor(tm, 2, 64));
            tm = fmaxf(tm, __shfl_xor(tm, 4, 64));
            tm = fmaxf(tm, __shfl_xor(tm, 8, 64));
            const float mn = fmaxf(m_run[r], tm);
            alpha_r[r] = __expf(m_run[r] - mn);
            m_run[r] = mn;
            float ss = 0.f;
            #pragma unroll
            for (int nt = 0; nt < 4; ++nt) {
                const float p = __expf(sv[nt][r] - mn);
                sv[nt][r] = p; ss += p;
            }
            ss += __shfl_xor(ss, 1, 64);
            ss += __shfl_xor(ss, 2, 64);
            ss += __shfl_xor(ss, 4, 64);
            ss += __shfl_xor(ss, 8, 64);
            l_run[r] = l_run[r] * alpha_r[r] + ss;
        }

        // ---- write P (bf16, per-wave 16-row region) ----
        #pragma unroll
        for (int nt = 0; nt < 4; ++nt)
            #pragma unroll
            for (int r = 0; r < 4; ++r)
                p_s[(wave * 16 + g * 4 + r) * PADK + nt * 16 + l] = f2bf(sv[nt][r]);
        __builtin_amdgcn_sched_barrier(0);  // keep PV reads below P writes

        // ---- rescale O accumulator ----
        #pragma unroll
        for (int nt = 0; nt < 4; ++nt)
            #pragma unroll
            for (int r = 0; r < 4; ++r)
                accO[nt][r] *= alpha_r[r];

        // ---- PV: accO[nt] += P . V ----
        short8 pa[2];
        #pragma unroll
        for (int kk = 0; kk < 2; ++kk)
            pa[kk] = *(const short8*)&p_s[(wave * 16 + l) * PADK + kk * 32 + g * 8];
        #pragma unroll
        for (int nt = 0; nt < 4; ++nt) {
            #pragma unroll
            for (int kk = 0; kk < 2; ++kk) {
                short8 bv8 = *(const short8*)&vT_s[(nt * 16 + l) * PADK + kk * 32 + g * 8];
                accO[nt] = __builtin_amdgcn_mfma_f32_16x16x32_bf16(pa[kk], bv8, accO[nt], 0, 0, 0);
            }
        }
    }

    // ---- epilogue: O = accO / l ----
    float inv[4];
    #pragma unroll
    for (int r = 0; r < 4; ++r) inv[r] = 1.0f / l_run[r];
    #pragma unroll
    for (int nt = 0; nt < 4; ++nt)
        #pragma unroll
        for (int r = 0; r < 4; ++r)
            O[(size_t)(b * 512 + i0 + wave * 16 + g * 4 + r) * 512 + h * 64 + nt * 16 + l]
                = accO[nt][r] * inv[r];
}

// ---------------------------------------------------------------------------
// Kernel 3: residual + LayerNorm + exact GELU. One wave per 512-elem row.
// ---------------------------------------------------------------------------
__global__ __launch_bounds__(256) void ln_gelu_kernel(
    const float* __restrict__ src, const float* __restrict__ O,
    const float* __restrict__ gamma, const float* __restrict__ beta,
    float* __restrict__ out)
{
    const int row  = blockIdx.x * 4 + (threadIdx.x >> 6);
    const int lane = threadIdx.x & 63;
    const float* s = &src[(size_t)row * 512];
    const float* o = &O[(size_t)row * 512];
    float x[8];
    float sum = 0.f;
    #pragma unroll
    for (int e = 0; e < 8; ++e) {
        x[e] = s[lane + e * 64] + o[lane + e * 64];
        sum += x[e];
    }
    #pragma unroll
    for (int off = 32; off >= 1; off >>= 1) sum += __shfl_xor(sum, off, 64);
    const float mean = sum * (1.0f / 512.0f);
    float var = 0.f;
    #pragma unroll
    for (int e = 0; e < 8; ++e) { float d = x[e] - mean; var += d * d; }
    #pragma unroll
    for (int off = 32; off >= 1; off >>= 1) var += __shfl_xor(var, off, 64);
    var *= (1.0f / 512.0f);
    const float inv = rsqrtf(var + 1e-5f);
    #pragma unroll
    for (int e = 0; e < 8; ++e) {
        const int c = lane + e * 64;
        float ln = (x[e] - mean) * inv * gamma[c] + beta[c];
        out[(size_t)row * 512 + c] = 0.5f * ln * (1.0f + erff(ln * 0.70710678118654752f));
    }
}

// ---------------------------------------------------------------------------
extern "C" void kernel_launch(void* const* d_in, const int* in_sizes, int n_in,
                              void* d_out, int out_size, void* d_ws, size_t ws_size,
                              hipStream_t stream)
{
    const float* src     = (const float*)d_in[0];
    const int*   seq_len = (const int*)  d_in[1];
    const float* pe      = (const float*)d_in[2];
    const float* Wq      = (const float*)d_in[3];
    const float* bq      = (const float*)d_in[4];
    const float* Wk      = (const float*)d_in[5];
    const float* bk      = (const float*)d_in[6];
    const float* Wv      = (const float*)d_in[7];
    const float* bv      = (const float*)d_in[8];
    const float* Wr      = (const float*)d_in[9];
    const float* br      = (const float*)d_in[10];
    const float* u       = (const float*)d_in[11];
    const float* v       = (const float*)d_in[12];
    const float* gamma   = (const float*)d_in[13];
    const float* beta    = (const float*)d_in[14];
    float* out = (float*)d_out;

    // workspace layout (byte offsets, 16B-aligned)
    char* w = (char*)d_ws;
    unsigned short* QKb     = (unsigned short*)(w);              // 4096*1024*2 =  8388608
    unsigned short* VTg     = (unsigned short*)(w + 8388608);    //  512*4096*2 =  4194304
    unsigned short* Rpb     = (unsigned short*)(w + 12582912);   // 1024*512*2  =  1048576
    float*          O       = (float*)         (w + 13631488);   // 4096*512*4  =  8388608
    unsigned short* src_bf  = (unsigned short*)(w + 22020096);   // 2097152*2   =  4194304
    unsigned short* pe_bf   = (unsigned short*)(w + 26214400);   //  524288*2   =  1048576
    unsigned short* Wcat_bf = (unsigned short*)(w + 27262976);   //  786432*2   =  1572864
    unsigned short* Wr_bf   = (unsigned short*)(w + 28835840);   //  262144*2   =   524288
    float*          bcat    = (float*)         (w + 29360128);   //    1536*4   =     6144
    // total ~29.4 MB

    convert_kernel<<<dim3(3590), 256, 0, stream>>>(
        src, pe, Wq, Wk, Wv, Wr, bq, bk, bv,
        src_bf, pe_bf, Wcat_bf, Wr_bf, bcat);

    // z=0: QK (x<8) + V^T (x>=8, operand-swapped); z=1: Rp
    mfma_nt_kernel<<<dim3(12, 32, 2), 256, 0, stream>>>(
        src_bf, Wcat_bf, bcat, QKb, VTg,
        pe_bf, Wr_bf, br, Rpb);

    attn_kernel<<<dim3(8, NHn, Bn), 256, 0, stream>>>(QKb, VTg, Rpb, u, v, seq_len, O);

    ln_gelu_kernel<<<dim3(Bn * Ln / 4), 256, 0, stream>>>(src, O, gamma, beta, out);
}